// Round 6
// baseline (409.687 us; speedup 1.0000x reference)
//
#include <hip/hip_runtime.h>

// Problem constants
#define B_N    64
#define S_LEN  1024
#define EMB    300
#define EMB_P  304              // padded token stride (halves) -> 608B, 16B-aligned
#define NGRAM  5
#define WPAD   1024
#define MTOT   (B_N * WPAD)     // 65536 rows
#define K1P    1536             // padded K for layer 1 (5*304 = 1520 -> 1536)
#define H0     512
#define H1D    256
#define H2D    128
#define NK1    (K1P / 32)       // 48 B-frag chunks for layer 1
#define NSTEP1 (K1P / 64)       // 24 K-loop steps (BK=64)

#define GATHER_BLOCKS ((MTOT * 38) / 256)            // 9728 (38 thr/token, half8)
#define WPREP_THREADS (H0 * K1P + H1D * H0 + H2D * H1D)
#define WPREP_BLOCKS  ((WPREP_THREADS + 255) / 256)  // 3712 exact

typedef _Float16 half8 __attribute__((ext_vector_type(8)));
typedef float  floatx4 __attribute__((ext_vector_type(4)));

typedef const __attribute__((address_space(1))) void* gptr_t;
typedef __attribute__((address_space(3))) void* sptr_t;

__device__ __forceinline__ void gload16(const void* g, void* s) {
  __builtin_amdgcn_global_load_lds((gptr_t)g, (sptr_t)s, 16, 0, 0);
}

// ---- fused prep: gather table[x]->fp16 (half8), zero out, weights ->
// frag-major, dual work-list scan.
// meta: [0]=nLive128 [1]=nLive64 [8..]=mt128 list [520..]=mt64 list
// NOTE (round-5 lesson): per-replay harness poison fills (~75us x2, 480MB
// at 80% HBM peak) dominate the non-kernel residue; they are untouchable.
__global__ void prep_kernel(const int* __restrict__ x,
                            const int* __restrict__ lengths,
                            const float* __restrict__ table,
                            _Float16* __restrict__ emb,
                            float* __restrict__ out,
                            const float* __restrict__ Ws,
                            const float* __restrict__ W1,
                            const float* __restrict__ W2,
                            _Float16* __restrict__ Bf1,
                            _Float16* __restrict__ Bf2,
                            _Float16* __restrict__ Bf3,
                            int* __restrict__ meta) {
  __shared__ int sN[64], sP[65], sN6[64], sP6[65];
  const int bid = blockIdx.x;
  if (bid < GATHER_BLOCKS) {
    if (bid < 32) out[bid * 256 + threadIdx.x] = 0.0f;  // zero 8192 outputs
    int tid = bid * 256 + threadIdx.x;
    int tok = tid / 38;
    int c   = tid - tok * 38;
    int valid = lengths[tok >> 10] - (NGRAM - 1);       // 1..1020
    int limit = ((valid + 127) & ~127) + (NGRAM - 1);   // live tokens only
    if ((tok & 1023) >= limit) return;
    int e = c << 3;                                     // 0..296 step 8
    const float* row = table + (size_t)x[tok] * EMB + e;
    float4 v0 = *(const float4*)row;
    float4 v1 = make_float4(0.0f, 0.0f, 0.0f, 0.0f);
    if (e + 4 < EMB) v1 = *(const float4*)(row + 4);    // e=296 -> pad 300..303
    union { half8 h8; _Float16 h[8]; } u;
    u.h[0] = (_Float16)v0.x; u.h[1] = (_Float16)v0.y;
    u.h[2] = (_Float16)v0.z; u.h[3] = (_Float16)v0.w;
    u.h[4] = (_Float16)v1.x; u.h[5] = (_Float16)v1.y;
    u.h[6] = (_Float16)v1.z; u.h[7] = (_Float16)v1.w;
    *(half8*)(emb + (size_t)tok * EMB_P + e) = u.h8;
  } else if (bid < GATHER_BLOCKS + WPREP_BLOCKS) {
    int tid = (bid - GATHER_BLOCKS) * 256 + threadIdx.x;
    const int NS = H0 * K1P;
    const int N1 = H1D * H0;
    const int N2 = H2D * H1D;
    if (tid < NS) {                       // layer1: coalesced over n
      int n = tid & 511, k = tid >> 9;    // k < 1536
      float v = 0.0f;
      if (k < NGRAM * EMB_P) {
        int tn = k / EMB_P, e = k - tn * EMB_P;
        if (e < EMB) v = Ws[(size_t)(tn * EMB + e) * H0 + n];
      }
      int idx = ((((n >> 4) * NK1 + (k >> 5)) << 6) + (((k >> 3) & 3) << 4) + (n & 15)) * 8 + (k & 7);
      Bf1[idx] = (_Float16)v;
    } else if (tid < NS + N1) {           // layer2: nK=16
      int t = tid - NS;
      int n = t & 255, k = t >> 8;        // k < 512
      float v = W1[(size_t)k * H1D + n];
      int idx = ((((n >> 4) * 16 + (k >> 5)) << 6) + (((k >> 3) & 3) << 4) + (n & 15)) * 8 + (k & 7);
      Bf2[idx] = (_Float16)v;
    } else if (tid < NS + N1 + N2) {      // layer3: nK=8
      int t = tid - (NS + N1);
      int n = t & 127, k = t >> 7;        // k < 256
      float v = W2[(size_t)k * H2D + n];
      int idx = ((((n >> 4) * 8 + (k >> 5)) << 6) + (((k >> 3) & 3) << 4) + (n & 15)) * 8 + (k & 7);
      Bf3[idx] = (_Float16)v;
    }
  } else {
    // ---- work-list build: deterministic prefix scans over 64 samples
    int t = threadIdx.x;
    if (t < 64) {
      int valid = lengths[t] - (NGRAM - 1);
      sN[t]  = (valid + 127) >> 7;   // 1..8  live 128-chunks
      sN6[t] = (valid + 63) >> 6;    // 1..16 live 64-chunks
    }
    __syncthreads();
    if (t == 0) {
      int s = 0, s6 = 0;
      for (int i = 0; i < 64; i++) {
        sP[i] = s;   s  += sN[i];
        sP6[i] = s6; s6 += sN6[i];
      }
      meta[0] = s; meta[1] = s6;
    }
    __syncthreads();
    if (t < 64) {
      int base = sP[t], n = sN[t];
      for (int i = 0; i < n; i++) meta[8 + base + i] = (t << 3) + i;
      int b6 = sP6[t], n6 = sN6[t];
      for (int i = 0; i < n6; i++) meta[520 + b6 + i] = (t << 4) + i;
    }
  }
}

// ------------------------- GEMM1 (verified round-3 structure): A LDS-staged
// (BK=64, dbuf, XOR-swizzled, gload16), B streamed frag-major with register
// ping-pong. ONE change vs round-3: __launch_bounds__(256,4) -> 4 blocks/CU
// (LDS 4x32=128<=160KB, VGPR 84 < 128 cap). The 4th co-resident block
// overlaps the per-step barrier vmcnt(0) drain (the known ~20% stall of this
// structure); round-5's B-LDS variant at 2 blocks/CU regressed -> reverted.
__global__ __launch_bounds__(256, 4)
void gemm1(const _Float16* __restrict__ A, const _Float16* __restrict__ Bf,
           const float* __restrict__ bias, _Float16* __restrict__ Cf,
           const int* __restrict__ meta) {
  __shared__ _Float16 sA[2][128 * 64];   // 2 x 16 KB

  const int nLive4 = meta[0] << 2;
  const int xcd = blockIdx.x & 7, bi = blockIdx.x >> 3;
  const int q = nLive4 >> 3, r = nLive4 & 7;
  if (bi >= q + (xcd < r ? 1 : 0)) return;
  const int L = xcd * q + (xcd < r ? xcd : r) + bi;   // bijection onto live4
  const int mt = meta[8 + (L >> 2)], nt = L & 3;

  const int tid  = threadIdx.x;
  const int wave = tid >> 6, lane = tid & 63;
  const int wr   = wave >> 1, wc = wave & 1;
  const int quad = lane >> 4, l16 = lane & 15;

  const long mBase = (long)mt << 7;
  const int  nBase = nt << 7;

  // staging: round p stages rows p*32..p*32+31; lane -> (row, slot=lane&7);
  // fetches global chunk c = slot ^ (row&7). LDS dst = uniform + lane*16B.
  const int srow0  = (wave << 3) + (lane >> 3);  // 0..31
  const int schunk = lane & 7;
  const _Float16* aG[4];
  int sOff[4];
#pragma unroll
  for (int p = 0; p < 4; p++) {
    int row = (p << 5) + srow0;
    int c   = schunk ^ (row & 7);
    aG[p]   = A + (mBase + row) * EMB_P + (c << 3);
    sOff[p] = (row << 6) + (schunk << 3);
  }

  const _Float16* bG[4];
#pragma unroll
  for (int j = 0; j < 4; j++)
    bG[j] = Bf + (((size_t)((nBase >> 4) + (wc << 2) + j) * NK1) << 9) + (lane << 3);

  // A-frag LDS offsets (constant over kk): row rr, wanted chunk s*4+quad
  int aOff[2][4];
#pragma unroll
  for (int s = 0; s < 2; s++)
#pragma unroll
    for (int i = 0; i < 4; i++) {
      int rr   = (wr << 6) + (i << 4) + l16;
      int slot = ((s << 2) + quad) ^ (l16 & 7);
      aOff[s][i] = (rr << 6) + (slot << 3);
    }

  floatx4 acc[4][4] = {};

  // prologue: A step 0 -> LDS buf0; B step 0 -> registers
#pragma unroll
  for (int p = 0; p < 4; p++) gload16(aG[p], &sA[0][sOff[p]]);
  half8 bCur[2][4], bNxt[2][4];
#pragma unroll
  for (int s = 0; s < 2; s++)
#pragma unroll
    for (int j = 0; j < 4; j++)
      bCur[s][j] = *(const half8*)(bG[j] + ((size_t)s << 9));

#pragma unroll 2
  for (int kk = 0; kk < NSTEP1; kk++) {
    const int cur = kk & 1;
    __syncthreads();
    if (kk + 1 < NSTEP1) {
      const int ko = (kk + 1) << 6;
#pragma unroll
      for (int p = 0; p < 4; p++) gload16(aG[p] + ko, &sA[cur ^ 1][sOff[p]]);
      // prefetch next step's B-frags: in flight across the whole MFMA phase
#pragma unroll
      for (int s = 0; s < 2; s++)
#pragma unroll
        for (int j = 0; j < 4; j++)
          bNxt[s][j] = *(const half8*)(bG[j] + (size_t)((((kk + 1) << 1) + s) << 9));
    }
#pragma unroll
    for (int s = 0; s < 2; s++) {
      half8 aFr[4];
#pragma unroll
      for (int i = 0; i < 4; i++)
        aFr[i] = *(const half8*)(&sA[cur][aOff[s][i]]);
#pragma unroll
      for (int i = 0; i < 4; i++)
#pragma unroll
        for (int j = 0; j < 4; j++)
          acc[i][j] = __builtin_amdgcn_mfma_f32_16x16x32_f16(aFr[i], bCur[s][j], acc[i][j], 0, 0, 0);
    }
#pragma unroll
    for (int s = 0; s < 2; s++)
#pragma unroll
      for (int j = 0; j < 4; j++)
        bCur[s][j] = bNxt[s][j];
  }

  // ---- epilogue: acc -> LDS (frag-major local) -> coalesced dwordx4 stores
  __syncthreads();
  _Float16* cs = &sA[0][0];  // 16384 halves = 32 KB, exactly one C-tile fp16
#pragma unroll
  for (int j = 0; j < 4; j++) {
    int cl = (wc << 6) + (j << 4) + l16;   // local col 0..127
    float bv = bias[nBase + cl];
    int ksl = cl >> 5;
    int sub_hi = ((cl >> 3) & 3) << 4;
    int c7 = cl & 7;
#pragma unroll
    for (int i = 0; i < 4; i++) {
      int m16l = (wr << 2) + i;
#pragma unroll
      for (int rr = 0; rr < 4; rr++) {
        int ml = (quad << 2) + rr;         // m & 15
        cs[(((m16l << 2) + ksl) << 9) + ((sub_hi + ml) << 3) + c7] =
            (_Float16)(acc[i][j][rr] + bv);
      }
    }
  }
  __syncthreads();
#pragma unroll
  for (int it = 0; it < 8; it++) {
    int cid = (it << 2) + wave;            // 0..31: chunk = (m16l, ksl)
    int m16l = cid >> 2, ksl = cid & 3;
    size_t g = ((size_t)(((mt << 3) + m16l) * 16 + (nt << 2) + ksl) << 9) + (lane << 3);
    *(half8*)(Cf + g) = *(const half8*)(cs + (cid << 9) + (lane << 3));
  }
}

// ------------------- fused GEMM2+GEMM3, M=64 tiles (verified round-3 form).
__global__ __launch_bounds__(256, 3)
void gemm23(const _Float16* __restrict__ Af, const _Float16* __restrict__ B2,
            const _Float16* __restrict__ B3, const float* __restrict__ bias1,
            const float* __restrict__ bias2, float* __restrict__ out,
            const int* __restrict__ lengths, const int* __restrict__ meta) {
  __shared__ _Float16 sH[16384];   // 32 KB: [m16l(4)][ks(8)][sub(64)][8]

  if ((int)blockIdx.x >= meta[1]) return;
  const int mt = meta[520 + blockIdx.x];    // 64-row tile id (b*16 + chunk)

  const int tid  = threadIdx.x;
  const int wave = tid >> 6, lane = tid & 63;
  const int wc   = wave;                    // 4 waves partition N=256
  const int quad = lane >> 4, l16 = lane & 15;

  const int b = mt >> 4;
  const int validw = lengths[b] - (NGRAM - 1);

  const _Float16* aB = Af + (((size_t)(mt << 2) * 16) << 9) + (lane << 3);
  const _Float16* bB = B2 + ((size_t)wc << 15) + (lane << 3);   // (wc*4)*16*512

  floatx4 acc2[4][4] = {};
  half8 aP[4], bP[4], aQ[4], bQ[4];

  auto loadA = [&](half8* d, int kk) {
#pragma unroll
    for (int i = 0; i < 4; i++)
      d[i] = *(const half8*)(aB + ((size_t)kk << 9) + ((size_t)i << 13));
  };
  auto loadB = [&](half8* d, int kk) {
#pragma unroll
    for (int j = 0; j < 4; j++)
      d[j] = *(const half8*)(bB + ((size_t)kk << 9) + ((size_t)j << 13));
  };
  auto mfmaStep = [&](const half8* aF, const half8* bF) {
    __builtin_amdgcn_s_setprio(1);
#pragma unroll
    for (int i = 0; i < 4; i++)
#pragma unroll
      for (int j = 0; j < 4; j++)
        acc2[i][j] = __builtin_amdgcn_mfma_f32_16x16x32_f16(aF[i], bF[j], acc2[i][j], 0, 0, 0);
    __builtin_amdgcn_s_setprio(0);
  };

  loadA(aP, 0); loadB(bP, 0);
#pragma unroll
  for (int kk = 0; kk < 16; kk += 2) {
    loadA(aQ, kk + 1); loadB(bQ, kk + 1);   // prefetch odd step
    mfmaStep(aP, bP);
    if (kk + 2 < 16) { loadA(aP, kk + 2); loadB(bP, kk + 2); }  // prefetch even
    mfmaStep(aQ, bQ);
  }

  // h2 tile -> LDS frag-major, +bias1, relu
#pragma unroll
  for (int j = 0; j < 4; j++) {
    int n = (wc << 6) + (j << 4) + l16;    // h2 col 0..255
    float bv = bias1[n];
    int ks = n >> 5;
    int sub_hi = ((n >> 3) & 3) << 4;
    int c7 = n & 7;
#pragma unroll
    for (int i = 0; i < 4; i++) {
#pragma unroll
      for (int rr = 0; rr < 4; rr++) {
        int ml = (quad << 2) + rr;
        sH[(((i << 3) + ks) << 9) + ((sub_hi + ml) << 3) + c7] =
            (_Float16)fmaxf(acc2[i][j][rr] + bv, 0.0f);
      }
    }
  }
  __syncthreads();

  // Phase B: G3 (K=256 from LDS), each wave owns 32 cols (2 n16-frags)
  const _Float16* b3R[2];
#pragma unroll
  for (int j = 0; j < 2; j++)
    b3R[j] = B3 + (((size_t)((wc << 1) + j) * 8) << 9) + (lane << 3);

  floatx4 acc3[4][2] = {};
#pragma unroll
  for (int ks = 0; ks < 8; ks++) {
    half8 aF[4], bF[2];
#pragma unroll
    for (int i = 0; i < 4; i++)
      aF[i] = *(const half8*)(sH + (((i << 3) + ks) << 9) + (lane << 3));
#pragma unroll
    for (int j = 0; j < 2; j++) bF[j] = *(const half8*)(b3R[j] + ((size_t)ks << 9));
    __builtin_amdgcn_s_setprio(1);
#pragma unroll
    for (int i = 0; i < 4; i++)
#pragma unroll
      for (int j = 0; j < 2; j++)
        acc3[i][j] = __builtin_amdgcn_mfma_f32_16x16x32_f16(aF[i], bF[j], acc3[i][j], 0, 0, 0);
    __builtin_amdgcn_s_setprio(0);
  }

  // fused relu + ragged-mean pooling (C/D: col=lane&15, row=quad*4+r)
  float inv = 1.0f / (float)validw;
  int wBase = (mt & 15) << 6;
#pragma unroll
  for (int j = 0; j < 2; j++) {
    int col = (wc << 5) + (j << 4) + l16;  // 0..127
    float bv = bias2[col];
    float p = 0.0f;
#pragma unroll
    for (int i = 0; i < 4; i++) {
#pragma unroll
      for (int rr = 0; rr < 4; rr++) {
        int w = wBase + (i << 4) + (quad << 2) + rr;
        float v = fmaxf(acc3[i][j][rr] + bv, 0.0f);
        p += (w < validw) ? v : 0.0f;
      }
    }
    p *= inv;
    p += __shfl_xor(p, 16, 64);
    p += __shfl_xor(p, 32, 64);
    if (quad == 0) atomicAdd(out + b * H2D + col, p);
  }
}

// ---------------------------------------------------------------- launcher
extern "C" void kernel_launch(void* const* d_in, const int* in_sizes, int n_in,
                              void* d_out, int out_size, void* d_ws, size_t ws_size,
                              hipStream_t stream) {
  const int*   x       = (const int*)d_in[0];
  const int*   lengths = (const int*)d_in[1];
  const float* table   = (const float*)d_in[2];
  const float* W_slide = (const float*)d_in[3];
  const float* b_slide = (const float*)d_in[4];
  const float* W1      = (const float*)d_in[5];
  const float* b1      = (const float*)d_in[6];
  const float* W2      = (const float*)d_in[7];
  const float* b2      = (const float*)d_in[8];
  float* out = (float*)d_out;

  // workspace (halves). emb +4096 pad: tail windows read past logical end
  // (garbage rows are masked in pooling; predicated select, no NaN prop).
  _Float16* ws  = (_Float16*)d_ws;
  _Float16* emb = ws;                                   // 64*1024*304
  _Float16* Bf1 = emb + (size_t)MTOT * EMB_P + 4096;    // 512*1536 frag-major
  _Float16* Bf2 = Bf1 + (size_t)H0 * K1P;               // 256*512  frag-major
  _Float16* Bf3 = Bf2 + (size_t)H1D * H0;               // 128*256  frag-major
  _Float16* h1f = Bf3 + (size_t)H2D * H1D;              // 65536*512 frag-major
  int*      meta = (int*)(h1f + (size_t)MTOT * H0);     // counts + lists

  prep_kernel<<<GATHER_BLOCKS + WPREP_BLOCKS + 1, 256, 0, stream>>>(
      x, lengths, table, emb, out, W_slide, W1, W2, Bf1, Bf2, Bf3, meta);
  // L1: win @ W_slide + b_slide -> h1f (frag-major), compacted live tiles
  gemm1<<<(MTOT / 128) * (H0 / 128), 256, 0, stream>>>(emb, Bf1, b_slide, h1f, meta);
  // L2+L3 fused: relu(h1@W1+b1) -> LDS -> relu(.@W2+b2) -> masked-mean pool
  gemm23<<<MTOT / 64, 256, 0, stream>>>(h1f, Bf2, Bf3, b1, b2, out, lengths, meta);
}

// Round 8
// 262.047 us; speedup vs baseline: 1.5634x; 1.5634x over previous
//
#include <hip/hip_runtime.h>

// Problem constants
#define B_N    64
#define S_LEN  1024
#define EMB    300
#define EMB_P  304              // padded token stride (halves) -> 608B, 16B-aligned
#define NGRAM  5
#define WPAD   1024
#define MTOT   (B_N * WPAD)     // 65536 rows
#define K1P    1536             // padded K for layer 1 (5*304 = 1520 -> 1536)
#define H0     512
#define H1D    256
#define H2D    128
#define NK1    (K1P / 32)       // 48 B-frag chunks for layer 1
#define NSTEP1 (K1P / 64)       // 24 K-loop steps (BK=64)

#define GATHER_BLOCKS ((MTOT * 38) / 256)            // 9728 (38 thr/token, half8)
#define WPREP_THREADS (H0 * K1P + H1D * H0 + H2D * H1D)
#define WPREP_BLOCKS  ((WPREP_THREADS + 255) / 256)  // 3712 exact

typedef _Float16 half8 __attribute__((ext_vector_type(8)));
typedef float  floatx4 __attribute__((ext_vector_type(4)));

typedef const __attribute__((address_space(1))) void* gptr_t;
typedef __attribute__((address_space(3))) void* sptr_t;

__device__ __forceinline__ void gload16(const void* g, void* s) {
  __builtin_amdgcn_global_load_lds((gptr_t)g, (sptr_t)s, 16, 0, 0);
}

// ---- fused prep: gather table[x]->fp16 (half8), zero out, weights ->
// frag-major, dual work-list scan.
// meta: [0]=nLive128 [1]=nLive64 [8..]=mt128 list [520..]=mt64 list
// NOTE (round-5 lesson): per-replay harness poison fills (~75us ea, 480MB
// at 80% HBM peak) dominate the non-kernel residue; untouchable from here.
__global__ void prep_kernel(const int* __restrict__ x,
                            const int* __restrict__ lengths,
                            const float* __restrict__ table,
                            _Float16* __restrict__ emb,
                            float* __restrict__ out,
                            const float* __restrict__ Ws,
                            const float* __restrict__ W1,
                            const float* __restrict__ W2,
                            _Float16* __restrict__ Bf1,
                            _Float16* __restrict__ Bf2,
                            _Float16* __restrict__ Bf3,
                            int* __restrict__ meta) {
  __shared__ int sN[64], sP[65], sN6[64], sP6[65];
  const int bid = blockIdx.x;
  if (bid < GATHER_BLOCKS) {
    if (bid < 32) out[bid * 256 + threadIdx.x] = 0.0f;  // zero 8192 outputs
    int tid = bid * 256 + threadIdx.x;
    int tok = tid / 38;
    int c   = tid - tok * 38;
    int valid = lengths[tok >> 10] - (NGRAM - 1);       // 1..1020
    int limit = ((valid + 127) & ~127) + (NGRAM - 1);   // live tokens only
    if ((tok & 1023) >= limit) return;
    int e = c << 3;                                     // 0..296 step 8
    const float* row = table + (size_t)x[tok] * EMB + e;
    float4 v0 = *(const float4*)row;
    float4 v1 = make_float4(0.0f, 0.0f, 0.0f, 0.0f);
    if (e + 4 < EMB) v1 = *(const float4*)(row + 4);    // e=296 -> pad 300..303
    union { half8 h8; _Float16 h[8]; } u;
    u.h[0] = (_Float16)v0.x; u.h[1] = (_Float16)v0.y;
    u.h[2] = (_Float16)v0.z; u.h[3] = (_Float16)v0.w;
    u.h[4] = (_Float16)v1.x; u.h[5] = (_Float16)v1.y;
    u.h[6] = (_Float16)v1.z; u.h[7] = (_Float16)v1.w;
    *(half8*)(emb + (size_t)tok * EMB_P + e) = u.h8;
  } else if (bid < GATHER_BLOCKS + WPREP_BLOCKS) {
    int tid = (bid - GATHER_BLOCKS) * 256 + threadIdx.x;
    const int NS = H0 * K1P;
    const int N1 = H1D * H0;
    const int N2 = H2D * H1D;
    if (tid < NS) {                       // layer1: coalesced over n
      int n = tid & 511, k = tid >> 9;    // k < 1536
      float v = 0.0f;
      if (k < NGRAM * EMB_P) {
        int tn = k / EMB_P, e = k - tn * EMB_P;
        if (e < EMB) v = Ws[(size_t)(tn * EMB + e) * H0 + n];
      }
      int idx = ((((n >> 4) * NK1 + (k >> 5)) << 6) + (((k >> 3) & 3) << 4) + (n & 15)) * 8 + (k & 7);
      Bf1[idx] = (_Float16)v;
    } else if (tid < NS + N1) {           // layer2: nK=16
      int t = tid - NS;
      int n = t & 255, k = t >> 8;        // k < 512
      float v = W1[(size_t)k * H1D + n];
      int idx = ((((n >> 4) * 16 + (k >> 5)) << 6) + (((k >> 3) & 3) << 4) + (n & 15)) * 8 + (k & 7);
      Bf2[idx] = (_Float16)v;
    } else if (tid < NS + N1 + N2) {      // layer3: nK=8
      int t = tid - (NS + N1);
      int n = t & 127, k = t >> 7;        // k < 256
      float v = W2[(size_t)k * H2D + n];
      int idx = ((((n >> 4) * 8 + (k >> 5)) << 6) + (((k >> 3) & 3) << 4) + (n & 15)) * 8 + (k & 7);
      Bf3[idx] = (_Float16)v;
    }
  } else {
    // ---- work-list build: deterministic prefix scans over 64 samples
    int t = threadIdx.x;
    if (t < 64) {
      int valid = lengths[t] - (NGRAM - 1);
      sN[t]  = (valid + 127) >> 7;   // 1..8  live 128-chunks
      sN6[t] = (valid + 63) >> 6;    // 1..16 live 64-chunks
    }
    __syncthreads();
    if (t == 0) {
      int s = 0, s6 = 0;
      for (int i = 0; i < 64; i++) {
        sP[i] = s;   s  += sN[i];
        sP6[i] = s6; s6 += sN6[i];
      }
      meta[0] = s; meta[1] = s6;
    }
    __syncthreads();
    if (t < 64) {
      int base = sP[t], n = sN[t];
      for (int i = 0; i < n; i++) meta[8 + base + i] = (t << 3) + i;
      int b6 = sP6[t], n6 = sN6[t];
      for (int i = 0; i < n6; i++) meta[520 + b6 + i] = (t << 4) + i;
    }
  }
}

// ------------------------- GEMM1: m97 structure — A AND B single-buffered
// in 32 KB LDS, 2 barriers per K-step (issue gload -> sync(drain) -> MFMA ->
// sync). The barrier drain is absorbed by 5 co-resident blocks/CU (LDS-bound
// 160/32; no B-reg ping-pong -> VGPR well under the (256,3) cap, no spill —
// round-6 lesson: (256,4) forced 64 VGPR and spilled 555MB to scratch).
// B staged once per block (was 2x redundant per wr-pair) -> half B L2 traffic.
// Staging lane-maps verified: A (round 3), B (round 5).
__global__ __launch_bounds__(256, 3)
void gemm1(const _Float16* __restrict__ A, const _Float16* __restrict__ Bf,
           const float* __restrict__ bias, _Float16* __restrict__ Cf,
           const int* __restrict__ meta) {
  __shared__ _Float16 sm[16384];   // 32 KB: [0..8191]=A tile, [8192..]=B tile

  const int nLive4 = meta[0] << 2;
  const int xcd = blockIdx.x & 7, bi = blockIdx.x >> 3;
  const int q = nLive4 >> 3, r = nLive4 & 7;
  if (bi >= q + (xcd < r ? 1 : 0)) return;
  const int L = xcd * q + (xcd < r ? xcd : r) + bi;   // bijection onto live4
  const int mt = meta[8 + (L >> 2)], nt = L & 3;

  const int tid  = threadIdx.x;
  const int wave = tid >> 6, lane = tid & 63;
  const int wr   = wave >> 1, wc = wave & 1;
  const int quad = lane >> 4, l16 = lane & 15;

  const long mBase = (long)mt << 7;
  const int  nBase = nt << 7;

  // A staging: round p stages rows p*32..p*32+31; lane -> (row, slot=lane&7);
  // fetches global chunk c = slot ^ (row&7). LDS dst = uniform + lane*16B.
  const int srow0  = (wave << 3) + (lane >> 3);  // 0..31
  const int schunk = lane & 7;
  const _Float16* aG[4];
  int sOffA[4];
#pragma unroll
  for (int p = 0; p < 4; p++) {
    int row = (p << 5) + srow0;
    int c   = schunk ^ (row & 7);
    aG[p]   = A + (mBase + row) * EMB_P + (c << 3);
    sOffA[p] = (row << 6) + (schunk << 3);
  }

  // B staging: 16 chunks of 1KB per step ([n16l(8)][s(2)] frag-major, each
  // chunk contiguous in global). Round p covers idx=p*256+tid:
  // n16l=idx>>7, s=(idx>>6)&1, lane_s=idx&63. dst = 8192 + idx*8 halves.
  const _Float16* bSrc[4];
  int sOffB[4];
#pragma unroll
  for (int p = 0; p < 4; p++) {
    int idx    = (p << 8) + tid;
    int n16l   = idx >> 7;
    int s      = (idx >> 6) & 1;
    int lane_s = idx & 63;
    bSrc[p]  = Bf + (((size_t)((nBase >> 4) + n16l) * NK1 + s) << 9) + (lane_s << 3);
    sOffB[p] = 8192 + (idx << 3);
  }

  // A-frag LDS offsets (constant over kk): row rr, wanted chunk s*4+quad
  int aOff[2][4];
#pragma unroll
  for (int s = 0; s < 2; s++)
#pragma unroll
    for (int i = 0; i < 4; i++) {
      int rr   = (wr << 6) + (i << 4) + l16;
      int slot = ((s << 2) + quad) ^ (l16 & 7);
      aOff[s][i] = (rr << 6) + (slot << 3);
    }
  // B-frag LDS offsets: chunk = (wc*4+j)*2+s; 64 lanes read one chunk
  // linearly (lane*16B) -> conflict-free.
  int bOff[2][4];
#pragma unroll
  for (int s = 0; s < 2; s++)
#pragma unroll
    for (int j = 0; j < 4; j++)
      bOff[s][j] = 8192 + ((((((wc << 2) + j) << 1) + s) << 9) + (lane << 3));

  floatx4 acc[4][4] = {};

#pragma unroll 2
  for (int kk = 0; kk < NSTEP1; kk++) {
    // barrier 1: all waves done reading previous step's tiles
    __syncthreads();
    const int koA = kk << 6;
    const size_t koB = (size_t)kk << 10;   // +2 chunks = 1024 halves per step
#pragma unroll
    for (int p = 0; p < 4; p++) gload16(aG[p] + koA, &sm[sOffA[p]]);
#pragma unroll
    for (int p = 0; p < 4; p++) gload16(bSrc[p] + koB, &sm[sOffB[p]]);
    // barrier 2: __syncthreads drains each wave's vmcnt(0) before s_barrier
    // -> all gload_lds writes landed; absorbed by 5 co-resident blocks.
    __syncthreads();
#pragma unroll
    for (int s = 0; s < 2; s++) {
      half8 aFr[4], bFr[4];
#pragma unroll
      for (int i = 0; i < 4; i++)
        aFr[i] = *(const half8*)(&sm[aOff[s][i]]);
#pragma unroll
      for (int j = 0; j < 4; j++)
        bFr[j] = *(const half8*)(&sm[bOff[s][j]]);
#pragma unroll
      for (int i = 0; i < 4; i++)
#pragma unroll
        for (int j = 0; j < 4; j++)
          acc[i][j] = __builtin_amdgcn_mfma_f32_16x16x32_f16(aFr[i], bFr[j], acc[i][j], 0, 0, 0);
    }
  }

  // ---- epilogue: acc -> LDS (frag-major local) -> coalesced dwordx4 stores
  __syncthreads();
  _Float16* cs = &sm[0];   // 16384 halves = 32 KB, exactly one C-tile fp16
#pragma unroll
  for (int j = 0; j < 4; j++) {
    int cl = (wc << 6) + (j << 4) + l16;   // local col 0..127
    float bv = bias[nBase + cl];
    int ksl = cl >> 5;
    int sub_hi = ((cl >> 3) & 3) << 4;
    int c7 = cl & 7;
#pragma unroll
    for (int i = 0; i < 4; i++) {
      int m16l = (wr << 2) + i;
#pragma unroll
      for (int rr = 0; rr < 4; rr++) {
        int ml = (quad << 2) + rr;         // m & 15
        cs[(((m16l << 2) + ksl) << 9) + ((sub_hi + ml) << 3) + c7] =
            (_Float16)(acc[i][j][rr] + bv);
      }
    }
  }
  __syncthreads();
#pragma unroll
  for (int it = 0; it < 8; it++) {
    int cid = (it << 2) + wave;            // 0..31: chunk = (m16l, ksl)
    int m16l = cid >> 2, ksl = cid & 3;
    size_t g = ((size_t)(((mt << 3) + m16l) * 16 + (nt << 2) + ksl) << 9) + (lane << 3);
    *(half8*)(Cf + g) = *(const half8*)(cs + (cid << 9) + (lane << 3));
  }
}

// ------------------- fused GEMM2+GEMM3, M=64 tiles (verified round-3 form).
__global__ __launch_bounds__(256, 3)
void gemm23(const _Float16* __restrict__ Af, const _Float16* __restrict__ B2,
            const _Float16* __restrict__ B3, const float* __restrict__ bias1,
            const float* __restrict__ bias2, float* __restrict__ out,
            const int* __restrict__ lengths, const int* __restrict__ meta) {
  __shared__ _Float16 sH[16384];   // 32 KB: [m16l(4)][ks(8)][sub(64)][8]

  if ((int)blockIdx.x >= meta[1]) return;
  const int mt = meta[520 + blockIdx.x];    // 64-row tile id (b*16 + chunk)

  const int tid  = threadIdx.x;
  const int wave = tid >> 6, lane = tid & 63;
  const int wc   = wave;                    // 4 waves partition N=256
  const int quad = lane >> 4, l16 = lane & 15;

  const int b = mt >> 4;
  const int validw = lengths[b] - (NGRAM - 1);

  const _Float16* aB = Af + (((size_t)(mt << 2) * 16) << 9) + (lane << 3);
  const _Float16* bB = B2 + ((size_t)wc << 15) + (lane << 3);   // (wc*4)*16*512

  floatx4 acc2[4][4] = {};
  half8 aP[4], bP[4], aQ[4], bQ[4];

  auto loadA = [&](half8* d, int kk) {
#pragma unroll
    for (int i = 0; i < 4; i++)
      d[i] = *(const half8*)(aB + ((size_t)kk << 9) + ((size_t)i << 13));
  };
  auto loadB = [&](half8* d, int kk) {
#pragma unroll
    for (int j = 0; j < 4; j++)
      d[j] = *(const half8*)(bB + ((size_t)kk << 9) + ((size_t)j << 13));
  };
  auto mfmaStep = [&](const half8* aF, const half8* bF) {
    __builtin_amdgcn_s_setprio(1);
#pragma unroll
    for (int i = 0; i < 4; i++)
#pragma unroll
      for (int j = 0; j < 4; j++)
        acc2[i][j] = __builtin_amdgcn_mfma_f32_16x16x32_f16(aF[i], bF[j], acc2[i][j], 0, 0, 0);
    __builtin_amdgcn_s_setprio(0);
  };

  loadA(aP, 0); loadB(bP, 0);
#pragma unroll
  for (int kk = 0; kk < 16; kk += 2) {
    loadA(aQ, kk + 1); loadB(bQ, kk + 1);   // prefetch odd step
    mfmaStep(aP, bP);
    if (kk + 2 < 16) { loadA(aP, kk + 2); loadB(bP, kk + 2); }  // prefetch even
    mfmaStep(aQ, bQ);
  }

  // h2 tile -> LDS frag-major, +bias1, relu
#pragma unroll
  for (int j = 0; j < 4; j++) {
    int n = (wc << 6) + (j << 4) + l16;    // h2 col 0..255
    float bv = bias1[n];
    int ks = n >> 5;
    int sub_hi = ((n >> 3) & 3) << 4;
    int c7 = n & 7;
#pragma unroll
    for (int i = 0; i < 4; i++) {
#pragma unroll
      for (int rr = 0; rr < 4; rr++) {
        int ml = (quad << 2) + rr;
        sH[(((i << 3) + ks) << 9) + ((sub_hi + ml) << 3) + c7] =
            (_Float16)fmaxf(acc2[i][j][rr] + bv, 0.0f);
      }
    }
  }
  __syncthreads();

  // Phase B: G3 (K=256 from LDS), each wave owns 32 cols (2 n16-frags)
  const _Float16* b3R[2];
#pragma unroll
  for (int j = 0; j < 2; j++)
    b3R[j] = B3 + (((size_t)((wc << 1) + j) * 8) << 9) + (lane << 3);

  floatx4 acc3[4][2] = {};
#pragma unroll
  for (int ks = 0; ks < 8; ks++) {
    half8 aF[4], bF[2];
#pragma unroll
    for (int i = 0; i < 4; i++)
      aF[i] = *(const half8*)(sH + (((i << 3) + ks) << 9) + (lane << 3));
#pragma unroll
    for (int j = 0; j < 2; j++) bF[j] = *(const half8*)(b3R[j] + ((size_t)ks << 9));
    __builtin_amdgcn_s_setprio(1);
#pragma unroll
    for (int i = 0; i < 4; i++)
#pragma unroll
      for (int j = 0; j < 2; j++)
        acc3[i][j] = __builtin_amdgcn_mfma_f32_16x16x32_f16(aF[i], bF[j], acc3[i][j], 0, 0, 0);
    __builtin_amdgcn_s_setprio(0);
  }

  // fused relu + ragged-mean pooling (C/D: col=lane&15, row=quad*4+r)
  float inv = 1.0f / (float)validw;
  int wBase = (mt & 15) << 6;
#pragma unroll
  for (int j = 0; j < 2; j++) {
    int col = (wc << 5) + (j << 4) + l16;  // 0..127
    float bv = bias2[col];
    float p = 0.0f;
#pragma unroll
    for (int i = 0; i < 4; i++) {
#pragma unroll
      for (int rr = 0; rr < 4; rr++) {
        int w = wBase + (i << 4) + (quad << 2) + rr;
        float v = fmaxf(acc3[i][j][rr] + bv, 0.0f);
        p += (w < validw) ? v : 0.0f;
      }
    }
    p *= inv;
    p += __shfl_xor(p, 16, 64);
    p += __shfl_xor(p, 32, 64);
    if (quad == 0) atomicAdd(out + b * H2D + col, p);
  }
}

// ---------------------------------------------------------------- launcher
extern "C" void kernel_launch(void* const* d_in, const int* in_sizes, int n_in,
                              void* d_out, int out_size, void* d_ws, size_t ws_size,
                              hipStream_t stream) {
  const int*   x       = (const int*)d_in[0];
  const int*   lengths = (const int*)d_in[1];
  const float* table   = (const float*)d_in[2];
  const float* W_slide = (const float*)d_in[3];
  const float* b_slide = (const float*)d_in[4];
  const float* W1      = (const float*)d_in[5];
  const float* b1      = (const float*)d_in[6];
  const float* W2      = (const float*)d_in[7];
  const float* b2      = (const float*)d_in[8];
  float* out = (float*)d_out;

  // workspace (halves). emb +4096 pad: tail windows read past logical end
  // (garbage rows are masked in pooling; predicated select, no NaN prop).
  _Float16* ws  = (_Float16*)d_ws;
  _Float16* emb = ws;                                   // 64*1024*304
  _Float16* Bf1 = emb + (size_t)MTOT * EMB_P + 4096;    // 512*1536 frag-major
  _Float16* Bf2 = Bf1 + (size_t)H0 * K1P;               // 256*512  frag-major
  _Float16* Bf3 = Bf2 + (size_t)H1D * H0;               // 128*256  frag-major
  _Float16* h1f = Bf3 + (size_t)H2D * H1D;              // 65536*512 frag-major
  int*      meta = (int*)(h1f + (size_t)MTOT * H0);     // counts + lists

  prep_kernel<<<GATHER_BLOCKS + WPREP_BLOCKS + 1, 256, 0, stream>>>(
      x, lengths, table, emb, out, W_slide, W1, W2, Bf1, Bf2, Bf3, meta);
  // L1: win @ W_slide + b_slide -> h1f (frag-major), compacted live tiles
  gemm1<<<(MTOT / 128) * (H0 / 128), 256, 0, stream>>>(emb, Bf1, b_slide, h1f, meta);
  // L2+L3 fused: relu(h1@W1+b1) -> LDS -> relu(.@W2+b2) -> masked-mean pool
  gemm23<<<MTOT / 64, 256, 0, stream>>>(h1f, Bf2, Bf3, b1, b2, out, lengths, meta);
}